// Round 5
// baseline (3265.135 us; speedup 1.0000x reference)
//
#include <hip/hip_runtime.h>
#include <hip/hip_bf16.h>
#include <cstddef>
#include <cstdint>

#define NBLK(n, b) (((n) + (b) - 1) / (b))

typedef __attribute__((ext_vector_type(8))) short short8;
typedef __attribute__((ext_vector_type(4))) float f32x4;

__device__ inline unsigned short f2bf(float f) {
  union { float f; unsigned u; } v; v.f = f;
  unsigned u = v.u;
  u += 0x7FFFu + ((u >> 16) & 1u);  // RNE
  return (unsigned short)(u >> 16);
}
__device__ inline float bflo(unsigned u) { union { unsigned u; float f; } v; v.u = u << 16; return v.f; }
__device__ inline float bfhi(unsigned u) { union { unsigned u; float f; } v; v.u = u & 0xFFFF0000u; return v.f; }

// Hardware LDS float atomic. Plain atomicAdd AND unsafeAtomicAdd on
// __shared__ float both lower to a CAS loop on this toolchain (R3/R4:
// identical 1178us, VALUBusy 1.2%, SGPR 112). Emit ds_add_f32 directly.
// Address = 32-bit LDS byte offset (addrspace(3) cast); offset: immediate
// walks the 8 channel words from one address VGPR.
__device__ inline unsigned lds_addr(float* p) {
  return (unsigned)(uintptr_t)(__attribute__((address_space(3))) float*)p;
}
#define DS_ADDF(a, off, val) \
  asm volatile("ds_add_f32 %0, %1 offset:" #off : : "v"(a), "v"(val))

// Bucketing: buckets of 512 dst nodes; node ids < 2^17 (N=100K).
// key = src | (localDst << 17) fits u32. Fixed-capacity padded buckets.
#define BSHIFT 9
#define BSIZE 512
#define CAPSHIFT 14
#define CAP 16384
#define ECHUNK 2048

// All bf16 feature tensors live in SLICE-TRANSPOSED layout:
//   element (node, ch) at half-index ((ch>>4) * N + node) * 16 + (ch & 15)
// i.e. T[g][N][16ch], 32 B per node per 16-ch slice. One slice = 3.2 MB -> fits
// an XCD's 4 MB L2; aggregation blocks use slice = blockIdx.x & 7 (XCD-affine
// via %8 round-robin). Confirmed R1-R4: FETCH at compulsory (~44 MB).

// ---------------- cast x -> bf16 sliced layout, prep packed weights ----------------
__global__ __launch_bounds__(256) void k_cast(
    const float* __restrict__ x, unsigned* __restrict__ xT, int N,
    const float* __restrict__ W1l, const float* __restrict__ W1r, unsigned short* __restrict__ Wb1,
    const float* __restrict__ W2l, const float* __restrict__ W2r, unsigned short* __restrict__ Wb2,
    const float* __restrict__ W3l, const float* __restrict__ W3r, unsigned short* __restrict__ Wb3) {
  int t = threadIdx.x;
  int b = blockIdx.x;
  int gCast = (N * 64 + 255) >> 8;
  if (b < gCast) {
    int i = b * 256 + t;
    if (i < N * 64) {
      float2 v = *(const float2*)(x + (size_t)i * 2);
      int node = i >> 6, j = i & 63;
      // word covers channels {2j, 2j+1}; slice g = j>>3, word-in-slice = j&7
      xT[((size_t)(j >> 3) * N + node) * 8 + (j & 7)] =
          (unsigned)f2bf(v.x) | ((unsigned)f2bf(v.y) << 16);
    }
    return;
  }
  b -= gCast;
  int ii = b * 256 + t;
  const float *Wl, *Wr; unsigned short* Wb;
  if (ii < 128 * 256) { Wl = W1l; Wr = W1r; Wb = Wb1; }
  else if (ii < 256 * 256) { Wl = W2l; Wr = W2r; Wb = Wb2; ii -= 128 * 256; }
  else { Wl = W3l; Wr = W3r; Wb = Wb3; ii -= 256 * 256; }
  int nrow = ii >> 8, k = ii & 255;
  float v = (k < 128) ? Wr[nrow * 128 + k] : Wl[nrow * 128 + (k - 128)];
  Wb[ii] = f2bf(v);
}

// ---------------- edge scatter into padded buckets (unsorted within bucket) ----------------
__global__ __launch_bounds__(256) void k_scatter(
    const void* __restrict__ edges, int* __restrict__ bucketCursor,
    unsigned* __restrict__ bucketed, int E, int NB) {
  __shared__ int h[1024];
  __shared__ int base2[1024];
  int t = threadIdx.x;
  int b = blockIdx.x;

  const unsigned* e32 = (const unsigned*)edges;
  int is64 = 1;
#pragma unroll
  for (int i = 0; i < 16; ++i)
    if (e32[2 * i + 1] != 0u) is64 = 0;

  for (int i = t; i < NB; i += 256) h[i] = 0;
  __syncthreads();
  int base_e = b * ECHUNK;
  unsigned key[8];
  int bkt[8];
#pragma unroll
  for (int k = 0; k < 8; ++k) {
    int e = base_e + k * 256 + t;
    bkt[k] = -1;
    if (e < E) {
      int s, d;
      if (is64) {
        s = (int)((const long long*)edges)[e];
        d = (int)((const long long*)edges)[(size_t)E + e];
      } else {
        s = ((const int*)edges)[e];
        d = ((const int*)edges)[(size_t)E + e];
      }
      bkt[k] = d >> BSHIFT;
      key[k] = (unsigned)s | ((unsigned)(d & (BSIZE - 1)) << 17);
      atomicAdd(&h[bkt[k]], 1);
    }
  }
  __syncthreads();
  for (int i = t; i < NB; i += 256) {
    int c = h[i];
    base2[i] = c ? atomicAdd(&bucketCursor[i], c) : 0;
    h[i] = 0;
  }
  __syncthreads();
#pragma unroll
  for (int k = 0; k < 8; ++k) {
    if (bkt[k] >= 0) {
      int r = atomicAdd(&h[bkt[k]], 1);
      int pos = base2[bkt[k]] + r;
      if (pos < CAP)
        bucketed[((size_t)bkt[k] << CAPSHIFT) + pos] = key[k];
    }
  }
}

// ---------------- per-bucket degree histogram ----------------
__global__ __launch_bounds__(256) void k_deg(const unsigned* __restrict__ bucketed,
                                             const int* __restrict__ bucketCursor,
                                             int* __restrict__ deg, int N) {
  __shared__ int h[512];
  int b = blockIdx.x;
  int t = threadIdx.x;
  h[t * 2] = 0; h[t * 2 + 1] = 0;
  __syncthreads();
  int cnt = min(bucketCursor[b], CAP);
  size_t s0 = (size_t)b << CAPSHIFT;
  for (int i = t; i < cnt; i += 256) atomicAdd(&h[bucketed[s0 + i] >> 17], 1);
  __syncthreads();
  int nodeBase = b << BSHIFT;
  if (nodeBase + t * 2 < N) deg[nodeBase + t * 2] = h[t * 2];
  if (nodeBase + t * 2 + 1 < N) deg[nodeBase + t * 2 + 1] = h[t * 2 + 1];
}

// ---------------- bucket-resident LDS-atomic mean aggregation (128-ch layers) ----
// One block per (slice g = bid&7, bucket b = bid>>3). Accumulate f32 sums for
// 512 nodes x 16 ch in LDS (stride 17 floats spreads banks under random ld).
// Dense unsorted edge stream: 2 lanes/edge, 16 B gather each, 2-edge unroll,
// 8 hardware ds_add_f32 per lane per edge-half. Epilogue amortized over 512 nodes.
__global__ __launch_bounds__(256) void k_agg_lds(
    const uint4* __restrict__ inT, const unsigned* __restrict__ bucketed,
    const int* __restrict__ bucketCursor, const int* __restrict__ deg,
    uint4* __restrict__ outT, int n) {
  __shared__ float hacc[BSIZE * 17];
  int g = blockIdx.x & 7;
  int b = blockIdx.x >> 3;
  int t = threadIdx.x;
  for (int i = t; i < BSIZE * 17; i += 256) hacc[i] = 0.f;
  __syncthreads();

  unsigned hbase = lds_addr(hacc);
  int cnt = min(bucketCursor[b], CAP);
  const unsigned* keys = bucketed + ((size_t)b << CAPSHIFT);
  const uint4* bp = inT + (size_t)g * n * 2;
  int e2 = t >> 1, sub = t & 1;
  unsigned subOff = hbase + (unsigned)sub * 32u;

  for (int base = 0; base < cnt; base += 256) {
    int i0 = base + e2;
    int i1 = base + 128 + e2;
    bool g0 = i0 < cnt, g1 = i1 < cnt;
    unsigned k0 = g0 ? keys[i0] : 0u;
    unsigned k1 = g1 ? keys[i1] : 0u;
    uint4 v0, v1;
    if (g0) v0 = bp[(size_t)(k0 & 0x1FFFFu) * 2 + sub];
    if (g1) v1 = bp[(size_t)(k1 & 0x1FFFFu) * 2 + sub];
    if (g0) {
      unsigned a = subOff + (k0 >> 17) * 68u;
      DS_ADDF(a, 0, bflo(v0.x)); DS_ADDF(a, 4, bfhi(v0.x));
      DS_ADDF(a, 8, bflo(v0.y)); DS_ADDF(a, 12, bfhi(v0.y));
      DS_ADDF(a, 16, bflo(v0.z)); DS_ADDF(a, 20, bfhi(v0.z));
      DS_ADDF(a, 24, bflo(v0.w)); DS_ADDF(a, 28, bfhi(v0.w));
    }
    if (g1) {
      unsigned a = subOff + (k1 >> 17) * 68u;
      DS_ADDF(a, 0, bflo(v1.x)); DS_ADDF(a, 4, bfhi(v1.x));
      DS_ADDF(a, 8, bflo(v1.y)); DS_ADDF(a, 12, bfhi(v1.y));
      DS_ADDF(a, 16, bflo(v1.z)); DS_ADDF(a, 20, bfhi(v1.z));
      DS_ADDF(a, 24, bflo(v1.w)); DS_ADDF(a, 28, bfhi(v1.w));
    }
  }
  // inline-asm DS ops are untracked by the compiler's waitcnt insertion
  asm volatile("s_waitcnt lgkmcnt(0)" ::: "memory");
  __syncthreads();

  int nodeBase = b << BSHIFT;
#pragma unroll
  for (int k = 0; k < 2; ++k) {
    int ln = t * 2 + k;
    int node = nodeBase + ln;
    if (node < n) {
      float sc = 1.0f / (float)max(deg[node], 1);
      const float* hp = hacc + ln * 17;
      uint4 o0, o1;
      o0.x = (unsigned)f2bf(hp[0] * sc) | ((unsigned)f2bf(hp[1] * sc) << 16);
      o0.y = (unsigned)f2bf(hp[2] * sc) | ((unsigned)f2bf(hp[3] * sc) << 16);
      o0.z = (unsigned)f2bf(hp[4] * sc) | ((unsigned)f2bf(hp[5] * sc) << 16);
      o0.w = (unsigned)f2bf(hp[6] * sc) | ((unsigned)f2bf(hp[7] * sc) << 16);
      o1.x = (unsigned)f2bf(hp[8] * sc) | ((unsigned)f2bf(hp[9] * sc) << 16);
      o1.y = (unsigned)f2bf(hp[10] * sc) | ((unsigned)f2bf(hp[11] * sc) << 16);
      o1.z = (unsigned)f2bf(hp[12] * sc) | ((unsigned)f2bf(hp[13] * sc) << 16);
      o1.w = (unsigned)f2bf(hp[14] * sc) | ((unsigned)f2bf(hp[15] * sc) << 16);
      outT[((size_t)g * n + node) * 2] = o0;
      outT[((size_t)g * n + node) * 2 + 1] = o1;
    }
  }
}

// ---------------- layer-3 bucket-resident aggregate: out += mean(y3) ----------------
// Same structure; 4 slices of 16 ch (y3 is 64-ch). Epilogue RMWs fp32 out.
__global__ __launch_bounds__(256) void k_agg64_lds(
    const uint4* __restrict__ y3T, const unsigned* __restrict__ bucketed,
    const int* __restrict__ bucketCursor, const int* __restrict__ deg,
    float* __restrict__ outp, int n) {
  __shared__ float hacc[BSIZE * 17];
  int g = blockIdx.x & 3;
  int b = blockIdx.x >> 2;
  int t = threadIdx.x;
  for (int i = t; i < BSIZE * 17; i += 256) hacc[i] = 0.f;
  __syncthreads();

  unsigned hbase = lds_addr(hacc);
  int cnt = min(bucketCursor[b], CAP);
  const unsigned* keys = bucketed + ((size_t)b << CAPSHIFT);
  const uint4* bp = y3T + (size_t)g * n * 2;
  int e2 = t >> 1, sub = t & 1;
  unsigned subOff = hbase + (unsigned)sub * 32u;

  for (int base = 0; base < cnt; base += 256) {
    int i0 = base + e2;
    int i1 = base + 128 + e2;
    bool g0 = i0 < cnt, g1 = i1 < cnt;
    unsigned k0 = g0 ? keys[i0] : 0u;
    unsigned k1 = g1 ? keys[i1] : 0u;
    uint4 v0, v1;
    if (g0) v0 = bp[(size_t)(k0 & 0x1FFFFu) * 2 + sub];
    if (g1) v1 = bp[(size_t)(k1 & 0x1FFFFu) * 2 + sub];
    if (g0) {
      unsigned a = subOff + (k0 >> 17) * 68u;
      DS_ADDF(a, 0, bflo(v0.x)); DS_ADDF(a, 4, bfhi(v0.x));
      DS_ADDF(a, 8, bflo(v0.y)); DS_ADDF(a, 12, bfhi(v0.y));
      DS_ADDF(a, 16, bflo(v0.z)); DS_ADDF(a, 20, bfhi(v0.z));
      DS_ADDF(a, 24, bflo(v0.w)); DS_ADDF(a, 28, bfhi(v0.w));
    }
    if (g1) {
      unsigned a = subOff + (k1 >> 17) * 68u;
      DS_ADDF(a, 0, bflo(v1.x)); DS_ADDF(a, 4, bfhi(v1.x));
      DS_ADDF(a, 8, bflo(v1.y)); DS_ADDF(a, 12, bfhi(v1.y));
      DS_ADDF(a, 16, bflo(v1.z)); DS_ADDF(a, 20, bfhi(v1.z));
      DS_ADDF(a, 24, bflo(v1.w)); DS_ADDF(a, 28, bfhi(v1.w));
    }
  }
  asm volatile("s_waitcnt lgkmcnt(0)" ::: "memory");
  __syncthreads();

  int nodeBase = b << BSHIFT;
#pragma unroll
  for (int k = 0; k < 2; ++k) {
    int ln = t * 2 + k;
    int node = nodeBase + ln;
    if (node < n) {
      int dg = deg[node];
      if (dg > 0) {
        float sc = 1.0f / (float)dg;
        const float* hp = hacc + ln * 17;
        float* op = outp + (size_t)node * 64 + g * 16;
        float4 a = *(float4*)op;
        float4 c = *(float4*)(op + 4);
        float4 d = *(float4*)(op + 8);
        float4 e = *(float4*)(op + 12);
        a.x += hp[0] * sc; a.y += hp[1] * sc; a.z += hp[2] * sc; a.w += hp[3] * sc;
        c.x += hp[4] * sc; c.y += hp[5] * sc; c.z += hp[6] * sc; c.w += hp[7] * sc;
        d.x += hp[8] * sc; d.y += hp[9] * sc; d.z += hp[10] * sc; d.w += hp[11] * sc;
        e.x += hp[12] * sc; e.y += hp[13] * sc; e.z += hp[14] * sc; e.w += hp[15] * sc;
        *(float4*)op = a;
        *(float4*)(op + 4) = c;
        *(float4*)(op + 8) = d;
        *(float4*)(op + 12) = e;
      }
    }
  }
}

// ---------------- MFMA GEMM: out = self@Wr.T + mean@Wl.T + b (layers 1-2) ----------------
// A operands read from sliced layout; output written to sliced layout (bf16).
template <int H, bool RELU>
__global__ __launch_bounds__(256) void k_gemm(
    const unsigned short* __restrict__ selfT, const unsigned short* __restrict__ meanT,
    const unsigned short* __restrict__ Wb, const float* __restrict__ bias,
    unsigned short* __restrict__ outT, int n) {
  constexpr int TN = H / 32;
  int lane = threadIdx.x & 63;
  int w = threadIdx.x >> 6;
  int wr = w & 1, wc = w >> 1;
  int nodeBase = blockIdx.x * 128 + wr * 64;
  int colBase = wc * (H / 2);
  int l15 = lane & 15, quad = lane >> 4;

  f32x4 acc[4][TN];
#pragma unroll
  for (int t = 0; t < 4; ++t)
#pragma unroll
    for (int j = 0; j < TN; ++j) acc[t][j] = (f32x4){0.f, 0.f, 0.f, 0.f};

#pragma unroll
  for (int c = 0; c < 8; ++c) {
    const unsigned short* A = (c < 4) ? selfT : meanT;
    int ko = (c & 3) * 32 + quad * 8;
    int gk = ko >> 4;    // 16-ch slice
    int wo = ko & 15;    // 0 or 8
    short8 af[4], bfr[TN];
#pragma unroll
    for (int t = 0; t < 4; ++t) {
      int row = min(nodeBase + t * 16 + l15, n - 1);
      af[t] = *(const short8*)(A + ((size_t)gk * n + row) * 16 + wo);
    }
#pragma unroll
    for (int j = 0; j < TN; ++j) {
      int cn = colBase + j * 16 + l15;
      bfr[j] = *(const short8*)(Wb + (size_t)cn * 256 + c * 32 + quad * 8);
    }
#pragma unroll
    for (int t = 0; t < 4; ++t)
#pragma unroll
      for (int j = 0; j < TN; ++j)
        acc[t][j] = __builtin_amdgcn_mfma_f32_16x16x32_bf16(af[t], bfr[j], acc[t][j], 0, 0, 0);
  }

#pragma unroll
  for (int j = 0; j < TN; ++j) {
    int col = colBase + j * 16 + l15;
    int gc = col >> 4;  // = wc*4 + j
    float bv = bias[col];
#pragma unroll
    for (int t = 0; t < 4; ++t) {
#pragma unroll
      for (int r = 0; r < 4; ++r) {
        int row = nodeBase + t * 16 + quad * 4 + r;
        if (row < n) {
          float v = acc[t][j][r] + bv;
          if (RELU) v = fmaxf(v, 0.f);
          outT[((size_t)gc * n + row) * 16 + l15] = f2bf(v);
        }
      }
    }
  }
}

// ---------------- layer-3 combined transform: out = h2@W3r.T + b3 (fp32); y3T = h2@W3l.T (bf16 sliced) ----------------
__global__ __launch_bounds__(256) void k_gemm3_both(
    const unsigned short* __restrict__ A,    // h2T sliced
    const unsigned short* __restrict__ Wb3,  // [64][256]: self half +0, mean half +128
    const float* __restrict__ bias,
    float* __restrict__ outp, unsigned short* __restrict__ y3T, int n) {
  int lane = threadIdx.x & 63;
  int w = threadIdx.x >> 6;
  int wr = w & 1, wc = w >> 1;
  int nodeBase = blockIdx.x * 128 + wr * 64;
  int l15 = lane & 15, quad = lane >> 4;
  int woff = wc ? 128 : 0;
  f32x4 acc[4][4];
#pragma unroll
  for (int t = 0; t < 4; ++t)
#pragma unroll
    for (int j = 0; j < 4; ++j) acc[t][j] = (f32x4){0.f, 0.f, 0.f, 0.f};
#pragma unroll
  for (int c = 0; c < 4; ++c) {
    int ko = c * 32 + quad * 8;
    int gk = ko >> 4;
    int wo = ko & 15;
    short8 af[4], bfr[4];
#pragma unroll
    for (int t = 0; t < 4; ++t) {
      int row = min(nodeBase + t * 16 + l15, n - 1);
      af[t] = *(const short8*)(A + ((size_t)gk * n + row) * 16 + wo);
    }
#pragma unroll
    for (int j = 0; j < 4; ++j) {
      int cn = j * 16 + l15;
      bfr[j] = *(const short8*)(Wb3 + (size_t)cn * 256 + woff + c * 32 + quad * 8);
    }
#pragma unroll
    for (int t = 0; t < 4; ++t)
#pragma unroll
      for (int j = 0; j < 4; ++j)
        acc[t][j] = __builtin_amdgcn_mfma_f32_16x16x32_bf16(af[t], bfr[j], acc[t][j], 0, 0, 0);
  }
#pragma unroll
  for (int j = 0; j < 4; ++j) {
    int col = j * 16 + l15;
    float bv = wc ? 0.f : bias[col];
#pragma unroll
    for (int t = 0; t < 4; ++t) {
#pragma unroll
      for (int r = 0; r < 4; ++r) {
        int row = nodeBase + t * 16 + quad * 4 + r;
        if (row < n) {
          float v = acc[t][j][r] + bv;
          if (wc) y3T[((size_t)j * n + row) * 16 + l15] = f2bf(v);
          else outp[(size_t)row * 64 + col] = v;
        }
      }
    }
  }
}

// ---------------- launch ----------------

extern "C" void kernel_launch(void* const* d_in, const int* in_sizes, int n_in,
                              void* d_out, int out_size, void* d_ws, size_t ws_size,
                              hipStream_t stream) {
  (void)n_in; (void)out_size; (void)ws_size;
  const float* x = (const float*)d_in[0];
  const void* edges = d_in[1];
  const float* W1l = (const float*)d_in[2];
  const float* W1r = (const float*)d_in[3];
  const float* b1 = (const float*)d_in[4];
  const float* W2l = (const float*)d_in[5];
  const float* W2r = (const float*)d_in[6];
  const float* b2 = (const float*)d_in[7];
  const float* W3l = (const float*)d_in[8];
  const float* W3r = (const float*)d_in[9];
  const float* b3 = (const float*)d_in[10];
  float* out = (float*)d_out;

  const int N = in_sizes[0] / 128;
  const int E = in_sizes[1] / 2;
  const int NB = (N + BSIZE - 1) >> BSHIFT;

  char* ws = (char*)d_ws;
  size_t off = 0;
  auto alloc = [&](size_t bytes) -> char* {
    char* p = ws + off;
    off = (off + bytes + 255) & ~(size_t)255;
    return p;
  };
  int* bucketCursor = (int*)alloc((size_t)NB * 4);
  unsigned* bucketed = (unsigned*)alloc((size_t)NB * CAP * 4);
  int* deg = (int*)alloc((size_t)N * 4);
  unsigned short* xT = (unsigned short*)alloc((size_t)N * 128 * 2);
  unsigned short* meanT = (unsigned short*)alloc((size_t)N * 128 * 2);
  unsigned short* h1T = (unsigned short*)alloc((size_t)N * 128 * 2);
  unsigned short* h2T = (unsigned short*)alloc((size_t)N * 128 * 2);
  unsigned short* y3T = (unsigned short*)alloc((size_t)N * 64 * 2);
  unsigned short* Wb1 = (unsigned short*)alloc(128 * 256 * 2);
  unsigned short* Wb2 = (unsigned short*)alloc(128 * 256 * 2);
  unsigned short* Wb3 = (unsigned short*)alloc(64 * 256 * 2);

  int gCast = NBLK(N * 64, 256) + 320;
  int gE = NBLK(E, ECHUNK);
  int gAgg = NB * 8;
  int gAgg64 = NB * 4;
  int gGemm = NBLK(N, 128);

  hipMemsetAsync(bucketCursor, 0, (size_t)NB * 4, stream);
  k_cast<<<gCast, 256, 0, stream>>>(x, (unsigned*)xT, N,
                                    W1l, W1r, Wb1, W2l, W2r, Wb2, W3l, W3r, Wb3);
  k_scatter<<<gE, 256, 0, stream>>>(edges, bucketCursor, bucketed, E, NB);
  k_deg<<<NB, 256, 0, stream>>>(bucketed, bucketCursor, deg, N);

  // layer 1
  k_agg_lds<<<gAgg, 256, 0, stream>>>((const uint4*)xT, bucketed, bucketCursor, deg,
                                      (uint4*)meanT, N);
  k_gemm<128, true><<<gGemm, 256, 0, stream>>>(xT, meanT, Wb1, b1, h1T, N);
  // layer 2
  k_agg_lds<<<gAgg, 256, 0, stream>>>((const uint4*)h1T, bucketed, bucketCursor, deg,
                                      (uint4*)meanT, N);
  k_gemm<128, true><<<gGemm, 256, 0, stream>>>(h1T, meanT, Wb2, b2, h2T, N);
  // layer 3: transform-first
  k_gemm3_both<<<gGemm, 256, 0, stream>>>(h2T, Wb3, b3, out, y3T, N);
  k_agg64_lds<<<gAgg64, 256, 0, stream>>>((const uint4*)y3T, bucketed, bucketCursor, deg,
                                          out, N);
}

// Round 6
// 507.010 us; speedup vs baseline: 6.4400x; 6.4400x over previous
//
#include <hip/hip_runtime.h>
#include <hip/hip_bf16.h>
#include <cstddef>
#include <cstdint>

#define NBLK(n, b) (((n) + (b) - 1) / (b))

typedef __attribute__((ext_vector_type(8))) short short8;
typedef __attribute__((ext_vector_type(4))) float f32x4;

__device__ inline unsigned short f2bf(float f) {
  union { float f; unsigned u; } v; v.f = f;
  unsigned u = v.u;
  u += 0x7FFFu + ((u >> 16) & 1u);  // RNE
  return (unsigned short)(u >> 16);
}
__device__ inline float bflo(unsigned u) { union { unsigned u; float f; } v; v.u = u << 16; return v.f; }
__device__ inline float bfhi(unsigned u) { union { unsigned u; float f; } v; v.u = u & 0xFFFF0000u; return v.f; }

// DEAD END (R3-R5): LDS-atomic accumulation. atomicAdd / unsafeAtomicAdd /
// inline-asm ds_add_f32 all measured bit-identical (1174-1179us, VALUBusy
// 1.2%, SQ_LDS_BANK_CONFLICT exactly 199936 each time): LDS atomics with 64
// divergent lane addresses serialize per-lane in the RMW unit (~2-3 cyc/lane
// -> 205M lane-atomics ~ 1.2ms). Do not revisit.

// CSR bucket sort: buckets of 512 nodes; node ids < 2^17 (N=100K).
// key = src | (localDst << 17) fits u32. Fixed-capacity padded buckets.
#define BSHIFT 9
#define BSIZE 512
#define CAPSHIFT 14
#define CAP 16384
#define ECHUNK 2048

// All bf16 feature tensors live in SLICE-TRANSPOSED layout:
//   element (node, ch) at half-index ((ch>>4) * N + node) * 16 + (ch & 15)
// i.e. T[g][N][16ch], 32 B per node per 16-ch slice. One slice = 3.2 MB -> fits
// an XCD's 4 MB L2; aggregation blocks use slice = blockIdx.x & 7 (XCD-affine
// via %8 round-robin). Confirmed R1-R5: FETCH at compulsory (~44 MB vs 179 MB
// for row-major rows).

// ---------------- cast x -> bf16 sliced layout, prep packed weights ----------------
__global__ __launch_bounds__(256) void k_cast(
    const float* __restrict__ x, unsigned* __restrict__ xT, int N,
    const float* __restrict__ W1l, const float* __restrict__ W1r, unsigned short* __restrict__ Wb1,
    const float* __restrict__ W2l, const float* __restrict__ W2r, unsigned short* __restrict__ Wb2,
    const float* __restrict__ W3l, const float* __restrict__ W3r, unsigned short* __restrict__ Wb3) {
  int t = threadIdx.x;
  int b = blockIdx.x;
  int gCast = (N * 64 + 255) >> 8;
  if (b < gCast) {
    int i = b * 256 + t;
    if (i < N * 64) {
      float2 v = *(const float2*)(x + (size_t)i * 2);
      int node = i >> 6, j = i & 63;
      // word covers channels {2j, 2j+1}; slice g = j>>3, word-in-slice = j&7
      xT[((size_t)(j >> 3) * N + node) * 8 + (j & 7)] =
          (unsigned)f2bf(v.x) | ((unsigned)f2bf(v.y) << 16);
    }
    return;
  }
  b -= gCast;
  int ii = b * 256 + t;
  const float *Wl, *Wr; unsigned short* Wb;
  if (ii < 128 * 256) { Wl = W1l; Wr = W1r; Wb = Wb1; }
  else if (ii < 256 * 256) { Wl = W2l; Wr = W2r; Wb = Wb2; ii -= 128 * 256; }
  else { Wl = W3l; Wr = W3r; Wb = Wb3; ii -= 256 * 256; }
  int nrow = ii >> 8, k = ii & 255;
  float v = (k < 128) ? Wr[nrow * 128 + k] : Wl[nrow * 128 + (k - 128)];
  Wb[ii] = f2bf(v);
}

// ---------------- edge scatter into padded buckets ----------------
__global__ __launch_bounds__(256) void k_scatter(
    const void* __restrict__ edges, int* __restrict__ bucketCursor,
    unsigned* __restrict__ bucketed, int E, int NB) {
  __shared__ int h[1024];
  __shared__ int base2[1024];
  int t = threadIdx.x;
  int b = blockIdx.x;

  const unsigned* e32 = (const unsigned*)edges;
  int is64 = 1;
#pragma unroll
  for (int i = 0; i < 16; ++i)
    if (e32[2 * i + 1] != 0u) is64 = 0;

  for (int i = t; i < NB; i += 256) h[i] = 0;
  __syncthreads();
  int base_e = b * ECHUNK;
  unsigned key[8];
  int bkt[8];
#pragma unroll
  for (int k = 0; k < 8; ++k) {
    int e = base_e + k * 256 + t;
    bkt[k] = -1;
    if (e < E) {
      int s, d;
      if (is64) {
        s = (int)((const long long*)edges)[e];
        d = (int)((const long long*)edges)[(size_t)E + e];
      } else {
        s = ((const int*)edges)[e];
        d = ((const int*)edges)[(size_t)E + e];
      }
      bkt[k] = d >> BSHIFT;
      key[k] = (unsigned)s | ((unsigned)(d & (BSIZE - 1)) << 17);
      atomicAdd(&h[bkt[k]], 1);
    }
  }
  __syncthreads();
  for (int i = t; i < NB; i += 256) {
    int c = h[i];
    base2[i] = c ? atomicAdd(&bucketCursor[i], c) : 0;
    h[i] = 0;
  }
  __syncthreads();
#pragma unroll
  for (int k = 0; k < 8; ++k) {
    if (bkt[k] >= 0) {
      int r = atomicAdd(&h[bkt[k]], 1);
      int pos = base2[bkt[k]] + r;
      if (pos < CAP)
        bucketed[((size_t)bkt[k] << CAPSHIFT) + pos] = key[k];
    }
  }
}

// ---------------- per-bucket CSR: rowStart + deg + srcSorted (padded layout) ----------------
__global__ __launch_bounds__(256) void k_csr(const unsigned* __restrict__ bucketed,
                                             const int* __restrict__ bucketCursor,
                                             int* __restrict__ rowStart, int* __restrict__ deg,
                                             int* __restrict__ srcSorted, int N, int NB) {
  __shared__ int h[512];
  __shared__ int excl[512];
  __shared__ int sd[256];
  int b = blockIdx.x;
  int t = threadIdx.x;
  int nodeBase = b << BSHIFT;
  int nNode = min(BSIZE, N - nodeBase);
  int cnt = min(bucketCursor[b], CAP);
  size_t s0 = (size_t)b << CAPSHIFT;
  h[t * 2] = 0; h[t * 2 + 1] = 0;
  __syncthreads();
  for (int i = t; i < cnt; i += 256) {
    int ld = bucketed[s0 + i] >> 17;
    atomicAdd(&h[ld], 1);
  }
  __syncthreads();
  int a0 = h[t * 2], a1 = h[t * 2 + 1];
  int s = a0 + a1;
  sd[t] = s;
  __syncthreads();
  for (int off = 1; off < 256; off <<= 1) {
    int xv = (t >= off) ? sd[t - off] : 0;
    __syncthreads();
    sd[t] += xv;
    __syncthreads();
  }
  int run = sd[t] - s;
  excl[t * 2] = run;
  excl[t * 2 + 1] = run + a0;
  if (t * 2 < nNode) {
    rowStart[nodeBase + t * 2] = (int)s0 + run;
    deg[nodeBase + t * 2] = a0;
  }
  if (t * 2 + 1 < nNode) {
    rowStart[nodeBase + t * 2 + 1] = (int)s0 + run + a0;
    deg[nodeBase + t * 2 + 1] = a1;
  }
  h[t * 2] = 0; h[t * 2 + 1] = 0;
  __syncthreads();
  for (int i = t; i < cnt; i += 256) {
    unsigned u = bucketed[s0 + i];
    int ld = u >> 17;
    int r = atomicAdd(&h[ld], 1);
    srcSorted[s0 + excl[ld] + r] = (int)(u & 0x1FFFFu);
  }
}

// ---------------- slice-sharded wave-cooperative mean aggregation (128-ch layers) ----
// grid.x = 8 * ceil(N/16); slice g = bid & 7 (XCD-affine). 4 waves/block,
// 4 nodes/wave (one per 16-lane quarter). Lane = (q in [0,4)) x (eg in [0,8))
// x (sub in [0,2)). Per-lane direct src loads (sequential per quarter ->
// coalesced, L1-hit), stride-8 edge slots with 2-deep clamped unroll: masked
// tail only wastes a duplicate gather address, never VALU adds (R2's 32-slot
// stride wasted ~100% of VALU at mean degree 16).
__global__ __launch_bounds__(256) void k_agg_slice(
    const uint4* __restrict__ inT, const int* __restrict__ rowStart,
    const int* __restrict__ deg, const int* __restrict__ srcs,
    uint4* __restrict__ outT, int n) {
  int g = blockIdx.x & 7;
  int lane = threadIdx.x & 63;
  int w = threadIdx.x >> 6;
  int q = lane >> 4;
  int eg = (lane >> 1) & 7;
  int sub = lane & 1;
  int node = (blockIdx.x >> 3) * 16 + w * 4 + q;
  bool valid = node < n;
  int nc = valid ? node : n - 1;
  int r0 = rowStart[nc];
  int dg = valid ? deg[nc] : 0;
  int r1 = r0 + dg;
  const uint4* bp = inT + (size_t)g * n * 2 + sub;
  float acc[8];
#pragma unroll
  for (int k = 0; k < 8; ++k) acc[k] = 0.f;

  for (int e = r0 + eg; e < r1; e += 16) {
    int e1 = e + 8;
    int s0 = srcs[e];
    int s1 = srcs[min(e1, r1 - 1)];
    uint4 v0 = bp[(size_t)s0 * 2];
    uint4 v1 = bp[(size_t)s1 * 2];
    acc[0] += bflo(v0.x); acc[1] += bfhi(v0.x);
    acc[2] += bflo(v0.y); acc[3] += bfhi(v0.y);
    acc[4] += bflo(v0.z); acc[5] += bfhi(v0.z);
    acc[6] += bflo(v0.w); acc[7] += bfhi(v0.w);
    if (e1 < r1) {
      acc[0] += bflo(v1.x); acc[1] += bfhi(v1.x);
      acc[2] += bflo(v1.y); acc[3] += bfhi(v1.y);
      acc[4] += bflo(v1.z); acc[5] += bfhi(v1.z);
      acc[6] += bflo(v1.w); acc[7] += bfhi(v1.w);
    }
  }

#pragma unroll
  for (int k = 0; k < 8; ++k) {
    acc[k] += __shfl_xor(acc[k], 2);
    acc[k] += __shfl_xor(acc[k], 4);
    acc[k] += __shfl_xor(acc[k], 8);
  }
  if (eg == 0 && valid) {
    float sc = 1.0f / (float)max(dg, 1);
    uint4 o;
    o.x = (unsigned)f2bf(acc[0] * sc) | ((unsigned)f2bf(acc[1] * sc) << 16);
    o.y = (unsigned)f2bf(acc[2] * sc) | ((unsigned)f2bf(acc[3] * sc) << 16);
    o.z = (unsigned)f2bf(acc[4] * sc) | ((unsigned)f2bf(acc[5] * sc) << 16);
    o.w = (unsigned)f2bf(acc[6] * sc) | ((unsigned)f2bf(acc[7] * sc) << 16);
    outT[((size_t)g * n + node) * 2 + sub] = o;
  }
}

// ---------------- layer-3 slice-sharded aggregate: out += mean(y3 over in-neighbors) ----
// grid.x = 4 * ceil(N/16); slice g = bid & 3 -> slice g L2-resident on XCDs {g, g+4}.
// Same structure as k_agg_slice; epilogue RMWs fp32 out.
__global__ __launch_bounds__(256) void k_agg64_slice(
    const uint4* __restrict__ y3T, const int* __restrict__ rowStart,
    const int* __restrict__ deg, const int* __restrict__ srcs,
    float* __restrict__ outp, int n) {
  int g = blockIdx.x & 3;
  int lane = threadIdx.x & 63;
  int w = threadIdx.x >> 6;
  int q = lane >> 4;
  int eg = (lane >> 1) & 7;
  int sub = lane & 1;
  int node = (blockIdx.x >> 2) * 16 + w * 4 + q;
  bool valid = node < n;
  int nc = valid ? node : n - 1;
  int r0 = rowStart[nc];
  int dg = valid ? deg[nc] : 0;
  int r1 = r0 + dg;
  const uint4* bp = y3T + (size_t)g * n * 2 + sub;
  float acc[8];
#pragma unroll
  for (int k = 0; k < 8; ++k) acc[k] = 0.f;

  for (int e = r0 + eg; e < r1; e += 16) {
    int e1 = e + 8;
    int s0 = srcs[e];
    int s1 = srcs[min(e1, r1 - 1)];
    uint4 v0 = bp[(size_t)s0 * 2];
    uint4 v1 = bp[(size_t)s1 * 2];
    acc[0] += bflo(v0.x); acc[1] += bfhi(v0.x);
    acc[2] += bflo(v0.y); acc[3] += bfhi(v0.y);
    acc[4] += bflo(v0.z); acc[5] += bfhi(v0.z);
    acc[6] += bflo(v0.w); acc[7] += bfhi(v0.w);
    if (e1 < r1) {
      acc[0] += bflo(v1.x); acc[1] += bfhi(v1.x);
      acc[2] += bflo(v1.y); acc[3] += bfhi(v1.y);
      acc[4] += bflo(v1.z); acc[5] += bfhi(v1.z);
      acc[6] += bflo(v1.w); acc[7] += bfhi(v1.w);
    }
  }

#pragma unroll
  for (int k = 0; k < 8; ++k) {
    acc[k] += __shfl_xor(acc[k], 2);
    acc[k] += __shfl_xor(acc[k], 4);
    acc[k] += __shfl_xor(acc[k], 8);
  }
  if (eg == 0 && valid && dg > 0) {
    float sc = 1.0f / (float)dg;
    float* op = outp + (size_t)node * 64 + g * 16 + sub * 8;
    float4 a = *(float4*)op;
    float4 c = *(float4*)(op + 4);
    a.x += acc[0] * sc; a.y += acc[1] * sc; a.z += acc[2] * sc; a.w += acc[3] * sc;
    c.x += acc[4] * sc; c.y += acc[5] * sc; c.z += acc[6] * sc; c.w += acc[7] * sc;
    *(float4*)op = a;
    *(float4*)(op + 4) = c;
  }
}

// ---------------- MFMA GEMM: out = self@Wr.T + mean@Wl.T + b (layers 1-2) ----------------
// A operands read from sliced layout; output written to sliced layout (bf16).
template <int H, bool RELU>
__global__ __launch_bounds__(256) void k_gemm(
    const unsigned short* __restrict__ selfT, const unsigned short* __restrict__ meanT,
    const unsigned short* __restrict__ Wb, const float* __restrict__ bias,
    unsigned short* __restrict__ outT, int n) {
  constexpr int TN = H / 32;
  int lane = threadIdx.x & 63;
  int w = threadIdx.x >> 6;
  int wr = w & 1, wc = w >> 1;
  int nodeBase = blockIdx.x * 128 + wr * 64;
  int colBase = wc * (H / 2);
  int l15 = lane & 15, quad = lane >> 4;

  f32x4 acc[4][TN];
#pragma unroll
  for (int t = 0; t < 4; ++t)
#pragma unroll
    for (int j = 0; j < TN; ++j) acc[t][j] = (f32x4){0.f, 0.f, 0.f, 0.f};

#pragma unroll
  for (int c = 0; c < 8; ++c) {
    const unsigned short* A = (c < 4) ? selfT : meanT;
    int ko = (c & 3) * 32 + quad * 8;
    int gk = ko >> 4;    // 16-ch slice
    int wo = ko & 15;    // 0 or 8
    short8 af[4], bfr[TN];
#pragma unroll
    for (int t = 0; t < 4; ++t) {
      int row = min(nodeBase + t * 16 + l15, n - 1);
      af[t] = *(const short8*)(A + ((size_t)gk * n + row) * 16 + wo);
    }
#pragma unroll
    for (int j = 0; j < TN; ++j) {
      int cn = colBase + j * 16 + l15;
      bfr[j] = *(const short8*)(Wb + (size_t)cn * 256 + c * 32 + quad * 8);
    }
#pragma unroll
    for (int t = 0; t < 4; ++t)
#pragma unroll
      for (int j = 0; j < TN; ++j)
        acc[t][j] = __builtin_amdgcn_mfma_f32_16x16x32_bf16(af[t], bfr[j], acc[t][j], 0, 0, 0);
  }

#pragma unroll
  for (int j = 0; j < TN; ++j) {
    int col = colBase + j * 16 + l15;
    int gc = col >> 4;  // = wc*4 + j
    float bv = bias[col];
#pragma unroll
    for (int t = 0; t < 4; ++t) {
#pragma unroll
      for (int r = 0; r < 4; ++r) {
        int row = nodeBase + t * 16 + quad * 4 + r;
        if (row < n) {
          float v = acc[t][j][r] + bv;
          if (RELU) v = fmaxf(v, 0.f);
          outT[((size_t)gc * n + row) * 16 + l15] = f2bf(v);
        }
      }
    }
  }
}

// ---------------- layer-3 combined transform: out = h2@W3r.T + b3 (fp32); y3T = h2@W3l.T (bf16 sliced) ----------------
__global__ __launch_bounds__(256) void k_gemm3_both(
    const unsigned short* __restrict__ A,    // h2T sliced
    const unsigned short* __restrict__ Wb3,  // [64][256]: self half +0, mean half +128
    const float* __restrict__ bias,
    float* __restrict__ outp, unsigned short* __restrict__ y3T, int n) {
  int lane = threadIdx.x & 63;
  int w = threadIdx.x >> 6;
  int wr = w & 1, wc = w >> 1;
  int nodeBase = blockIdx.x * 128 + wr * 64;
  int l15 = lane & 15, quad = lane >> 4;
  int woff = wc ? 128 : 0;
  f32x4 acc[4][4];
#pragma unroll
  for (int t = 0; t < 4; ++t)
#pragma unroll
    for (int j = 0; j < 4; ++j) acc[t][j] = (f32x4){0.f, 0.f, 0.f, 0.f};
#pragma unroll
  for (int c = 0; c < 4; ++c) {
    int ko = c * 32 + quad * 8;
    int gk = ko >> 4;
    int wo = ko & 15;
    short8 af[4], bfr[4];
#pragma unroll
    for (int t = 0; t < 4; ++t) {
      int row = min(nodeBase + t * 16 + l15, n - 1);
      af[t] = *(const short8*)(A + ((size_t)gk * n + row) * 16 + wo);
    }
#pragma unroll
    for (int j = 0; j < 4; ++j) {
      int cn = j * 16 + l15;
      bfr[j] = *(const short8*)(Wb3 + (size_t)cn * 256 + woff + c * 32 + quad * 8);
    }
#pragma unroll
    for (int t = 0; t < 4; ++t)
#pragma unroll
      for (int j = 0; j < 4; ++j)
        acc[t][j] = __builtin_amdgcn_mfma_f32_16x16x32_bf16(af[t], bfr[j], acc[t][j], 0, 0, 0);
  }
#pragma unroll
  for (int j = 0; j < 4; ++j) {
    int col = j * 16 + l15;
    float bv = wc ? 0.f : bias[col];
#pragma unroll
    for (int t = 0; t < 4; ++t) {
#pragma unroll
      for (int r = 0; r < 4; ++r) {
        int row = nodeBase + t * 16 + quad * 4 + r;
        if (row < n) {
          float v = acc[t][j][r] + bv;
          if (wc) y3T[((size_t)j * n + row) * 16 + l15] = f2bf(v);
          else outp[(size_t)row * 64 + col] = v;
        }
      }
    }
  }
}

// ---------------- launch ----------------

extern "C" void kernel_launch(void* const* d_in, const int* in_sizes, int n_in,
                              void* d_out, int out_size, void* d_ws, size_t ws_size,
                              hipStream_t stream) {
  (void)n_in; (void)out_size; (void)ws_size;
  const float* x = (const float*)d_in[0];
  const void* edges = d_in[1];
  const float* W1l = (const float*)d_in[2];
  const float* W1r = (const float*)d_in[3];
  const float* b1 = (const float*)d_in[4];
  const float* W2l = (const float*)d_in[5];
  const float* W2r = (const float*)d_in[6];
  const float* b2 = (const float*)d_in[7];
  const float* W3l = (const float*)d_in[8];
  const float* W3r = (const float*)d_in[9];
  const float* b3 = (const float*)d_in[10];
  float* out = (float*)d_out;

  const int N = in_sizes[0] / 128;
  const int E = in_sizes[1] / 2;
  const int NB = (N + BSIZE - 1) >> BSHIFT;

  char* ws = (char*)d_ws;
  size_t off = 0;
  auto alloc = [&](size_t bytes) -> char* {
    char* p = ws + off;
    off = (off + bytes + 255) & ~(size_t)255;
    return p;
  };
  int* bucketCursor = (int*)alloc((size_t)NB * 4);
  unsigned* bucketed = (unsigned*)alloc((size_t)NB * CAP * 4);
  int* rowStart = (int*)alloc((size_t)N * 4);
  int* deg = (int*)alloc((size_t)N * 4);
  int* srcSorted = (int*)alloc((size_t)NB * CAP * 4);
  unsigned short* xT = (unsigned short*)alloc((size_t)N * 128 * 2);
  unsigned short* meanT = (unsigned short*)alloc((size_t)N * 128 * 2);
  unsigned short* h1T = (unsigned short*)alloc((size_t)N * 128 * 2);
  unsigned short* h2T = (unsigned short*)alloc((size_t)N * 128 * 2);
  unsigned short* y3T = (unsigned short*)alloc((size_t)N * 64 * 2);
  unsigned short* Wb1 = (unsigned short*)alloc(128 * 256 * 2);
  unsigned short* Wb2 = (unsigned short*)alloc(128 * 256 * 2);
  unsigned short* Wb3 = (unsigned short*)alloc(64 * 256 * 2);

  int gCast = NBLK(N * 64, 256) + 320;
  int gE = NBLK(E, ECHUNK);
  int gAgg = NBLK(N, 16) * 8;
  int gAgg64 = NBLK(N, 16) * 4;
  int gGemm = NBLK(N, 128);

  hipMemsetAsync(bucketCursor, 0, (size_t)NB * 4, stream);
  k_cast<<<gCast, 256, 0, stream>>>(x, (unsigned*)xT, N,
                                    W1l, W1r, Wb1, W2l, W2r, Wb2, W3l, W3r, Wb3);
  k_scatter<<<gE, 256, 0, stream>>>(edges, bucketCursor, bucketed, E, NB);
  k_csr<<<NB, 256, 0, stream>>>(bucketed, bucketCursor, rowStart, deg, srcSorted, N, NB);

  // layer 1
  k_agg_slice<<<gAgg, 256, 0, stream>>>((const uint4*)xT, rowStart, deg, srcSorted,
                                        (uint4*)meanT, N);
  k_gemm<128, true><<<gGemm, 256, 0, stream>>>(xT, meanT, Wb1, b1, h1T, N);
  // layer 2
  k_agg_slice<<<gAgg, 256, 0, stream>>>((const uint4*)h1T, rowStart, deg, srcSorted,
                                        (uint4*)meanT, N);
  k_gemm<128, true><<<gGemm, 256, 0, stream>>>(h1T, meanT, Wb2, b2, h2T, N);
  // layer 3: transform-first
  k_gemm3_both<<<gGemm, 256, 0, stream>>>(h2T, Wb3, b3, out, y3T, N);
  k_agg64_slice<<<gAgg64, 256, 0, stream>>>((const uint4*)y3T, rowStart, deg, srcSorted,
                                            out, N);
}